// Round 1
// baseline (598.304 us; speedup 1.0000x reference)
//
#include <hip/hip_runtime.h>

// out[i] = sum_j relu(adjacency[i,j] * Linv[i,j]) * W[j] + b
// N = 8192. Inputs (fp32): x_e (unused), Linv, adjacency, W[1,N], b[1].
// Output: fp32 [N,1].

#define NDIM 8192
#define BLOCK 256
#define F4_PER_ROW (NDIM / 4)          // 2048 float4 per row
#define ITERS (F4_PER_ROW / BLOCK)     // 8 float4 loads per thread per array

__global__ __launch_bounds__(BLOCK) void dist2cycle_row_reduce(
    const float* __restrict__ Linv,
    const float* __restrict__ adj,
    const float* __restrict__ W,
    const float* __restrict__ b,
    float* __restrict__ out)
{
    const int row = blockIdx.x;
    const int tid = threadIdx.x;

    const float4* __restrict__ lrow = (const float4*)(Linv + (size_t)row * NDIM);
    const float4* __restrict__ arow = (const float4*)(adj  + (size_t)row * NDIM);
    const float4* __restrict__ w4   = (const float4*)W;

    float acc = 0.0f;

    #pragma unroll
    for (int k = 0; k < ITERS; ++k) {
        const int idx = tid + k * BLOCK;   // lane-contiguous -> coalesced 16B/lane
        float4 l = lrow[idx];
        float4 a = arow[idx];
        float4 w = w4[idx];

        float m0 = a.x * l.x;
        float m1 = a.y * l.y;
        float m2 = a.z * l.z;
        float m3 = a.w * l.w;
        m0 = m0 > 0.0f ? m0 : 0.0f;
        m1 = m1 > 0.0f ? m1 : 0.0f;
        m2 = m2 > 0.0f ? m2 : 0.0f;
        m3 = m3 > 0.0f ? m3 : 0.0f;

        acc = fmaf(m0, w.x, acc);
        acc = fmaf(m1, w.y, acc);
        acc = fmaf(m2, w.z, acc);
        acc = fmaf(m3, w.w, acc);
    }

    // wave-level reduction (wave = 64 lanes on CDNA)
    #pragma unroll
    for (int off = 32; off > 0; off >>= 1)
        acc += __shfl_down(acc, off, 64);

    __shared__ float warp_sums[BLOCK / 64];
    const int wave = tid >> 6;
    const int lane = tid & 63;
    if (lane == 0) warp_sums[wave] = acc;
    __syncthreads();

    if (tid == 0) {
        float total = 0.0f;
        #pragma unroll
        for (int w = 0; w < BLOCK / 64; ++w) total += warp_sums[w];
        out[row] = total + b[0];
    }
}

extern "C" void kernel_launch(void* const* d_in, const int* in_sizes, int n_in,
                              void* d_out, int out_size, void* d_ws, size_t ws_size,
                              hipStream_t stream) {
    // setup_inputs order: x_e, Linv, adjacency, W, b  (all fp32)
    const float* Linv = (const float*)d_in[1];
    const float* adj  = (const float*)d_in[2];
    const float* W    = (const float*)d_in[3];
    const float* b    = (const float*)d_in[4];
    float* out        = (float*)d_out;

    dist2cycle_row_reduce<<<NDIM, BLOCK, 0, stream>>>(Linv, adj, W, b, out);
}

// Round 2
// 569.172 us; speedup vs baseline: 1.0512x; 1.0512x over previous
//
#include <hip/hip_runtime.h>

// out[i] = sum_j relu(adjacency[i,j] * Linv[i,j]) * W[j] + b
// N = 8192. Inputs (fp32): x_e (unused), Linv, adjacency, W[1,N], b[1].
// Output: fp32 [N,1]. Memory-bound: 512 MiB must-read -> ~85 us at 6.3 TB/s.

typedef float f4 __attribute__((ext_vector_type(4)));

#define NDIM 8192
#define BLOCK 256
#define ROWS_PER_BLOCK (BLOCK / 64)         // one 64-lane wave per row
#define GRID (NDIM / ROWS_PER_BLOCK)        // 2048 blocks = 8 blocks/CU
#define ITERS (NDIM / 4 / 64)               // 32 float4 per lane per array

__global__ __launch_bounds__(BLOCK) void dist2cycle_row_reduce(
    const float* __restrict__ Linv,
    const float* __restrict__ adj,
    const float* __restrict__ W,
    const float* __restrict__ b,
    float* __restrict__ out)
{
    const int wave = threadIdx.x >> 6;
    const int lane = threadIdx.x & 63;
    const int row  = blockIdx.x * ROWS_PER_BLOCK + wave;

    const f4* __restrict__ lrow = (const f4*)(Linv + (size_t)row * NDIM);
    const f4* __restrict__ arow = (const f4*)(adj  + (size_t)row * NDIM);
    const f4* __restrict__ w4   = (const f4*)W;

    float acc = 0.0f;

    // Streamed-once data: non-temporal loads keep L2/L3 clean for W.
    // unroll 8 -> ~16 NT loads in flight per wave; plenty of MLP at any occupancy.
    #pragma unroll 8
    for (int k = 0; k < ITERS; ++k) {
        const int idx = lane + (k << 6);     // lane-contiguous -> coalesced 16B/lane
        f4 l = __builtin_nontemporal_load(lrow + idx);
        f4 a = __builtin_nontemporal_load(arow + idx);
        f4 w = w4[idx];                      // reused across all rows -> cached

        float m0 = a.x * l.x;
        float m1 = a.y * l.y;
        float m2 = a.z * l.z;
        float m3 = a.w * l.w;
        m0 = m0 > 0.0f ? m0 : 0.0f;
        m1 = m1 > 0.0f ? m1 : 0.0f;
        m2 = m2 > 0.0f ? m2 : 0.0f;
        m3 = m3 > 0.0f ? m3 : 0.0f;

        acc = fmaf(m0, w.x, acc);
        acc = fmaf(m1, w.y, acc);
        acc = fmaf(m2, w.z, acc);
        acc = fmaf(m3, w.w, acc);
    }

    // wave-only reduction: no LDS, no barrier
    #pragma unroll
    for (int off = 32; off > 0; off >>= 1)
        acc += __shfl_down(acc, off, 64);

    if (lane == 0)
        out[row] = acc + b[0];
}

extern "C" void kernel_launch(void* const* d_in, const int* in_sizes, int n_in,
                              void* d_out, int out_size, void* d_ws, size_t ws_size,
                              hipStream_t stream) {
    // setup_inputs order: x_e, Linv, adjacency, W, b  (all fp32)
    const float* Linv = (const float*)d_in[1];
    const float* adj  = (const float*)d_in[2];
    const float* W    = (const float*)d_in[3];
    const float* b    = (const float*)d_in[4];
    float* out        = (float*)d_out;

    dist2cycle_row_reduce<<<GRID, BLOCK, 0, stream>>>(Linv, adj, W, b, out);
}